// Round 15
// baseline (130.773 us; speedup 1.0000x reference)
//
#include <hip/hip_runtime.h>
#include <cstdint>
#include <cstddef>

typedef __bf16 bf16x8 __attribute__((ext_vector_type(8)));
typedef __bf16 bf16x2 __attribute__((ext_vector_type(2)));
typedef float f32x4 __attribute__((ext_vector_type(4)));

#define L_SEQ 32768
#define H_DIM 512
#define P_DIM 256
#define NP2   512      // 2P = K and N of both GEMMs
#define CHUNK 32
#define NCHUNK 1024    // L / CHUNK
#define NSUPER 32      // NCHUNK / 32

__device__ __forceinline__ void gload_lds16(const void* g, void* l) {
    __builtin_amdgcn_global_load_lds(
        (const __attribute__((address_space(1))) void*)g,
        (__attribute__((address_space(3))) void*)l,
        16, 0, 0);
}

// ---------------- fused setup: prep (block 0) | build B/C (blocks 1..1024) |
// cast u->bf16 (blocks 1025..9216). Builders recompute coef inline (p uniform
// per block -> scalar transcendentals, free).
// par layout (floats): [0]=Ar [256]=Ai [1024]=PowR(Lbar^32) [1280]=PowI
//                      [1536]=ldr [1792]=ldi
__global__ void setup_kernel(const float* __restrict__ Lre, const float* __restrict__ Lim,
                             const float* __restrict__ lstep,
                             const float* __restrict__ Bre, const float* __restrict__ Bim,
                             const float* __restrict__ Cre, const float* __restrict__ Cim,
                             const float4* __restrict__ uin,
                             float* __restrict__ par,
                             __bf16* __restrict__ Bt, __bf16* __restrict__ Ct,
                             bf16x8* __restrict__ Ubf) {
    int b = blockIdx.x;
    if (b == 0) {
        int p = threadIdx.x;
        float lr = fminf(Lre[p], -1e-4f);       // clip_eigs
        float li = Lim[p];
        float st = expf(lstep[p]);
        float ldr = lr * st;
        float ldi = li * st;
        float er = expf(ldr);
        par[p]        = er * cosf(ldi);         // Ar
        par[256 + p]  = er * sinf(ldi);         // Ai
        float e32  = expf((float)CHUNK * ldr);
        float ph32 = (float)CHUNK * ldi;
        par[1024 + p] = e32 * cosf(ph32);       // PowR = Re(Lbar^32)
        par[1280 + p] = e32 * sinf(ph32);       // PowI
        par[1536 + p] = ldr;
        par[1792 + p] = ldi;
    } else if (b <= 1024) {
        int bb = b - 1;
        if (bb < 512) {
            int idx = bb * 256 + threadIdx.x;   // [0, P*H)
            int p = idx >> 9;                   // uniform per block
            float lr = fminf(Lre[p], -1e-4f);
            float li = Lim[p];
            float st = expf(lstep[p]);
            float er = expf(lr * st);
            float ar = er * cosf(li * st);
            float ai = er * sinf(li * st);
            float den = lr * lr + li * li;
            float mr = ar - 1.0f, mi = ai;
            float cr = (mr * lr + mi * li) / den;   // coef = (Lbar-1)/Lambda
            float ci = (mi * lr - mr * li) / den;
            float br = Bre[idx], bi = Bim[idx];
            int h = idx & 511;
            Bt[(size_t)p * NP2 + h]         = (__bf16)(cr * br - ci * bi);
            Bt[(size_t)(256 + p) * NP2 + h] = (__bf16)(cr * bi + ci * br);
        } else {
            int idx = (bb - 512) * 256 + threadIdx.x;   // [0, H*P)
            int h = idx >> 8;
            int q = idx & 255;
            Ct[(size_t)h * NP2 + q]       = (__bf16)( 2.0f * Cre[idx]);
            Ct[(size_t)h * NP2 + 256 + q] = (__bf16)(-2.0f * Cim[idx]);
        }
    } else {
        int i = (b - 1025) * 256 + threadIdx.x;     // [0, L*H/8)
        float4 a = uin[2 * i], c = uin[2 * i + 1];
        bf16x8 v;
        v[0] = (__bf16)a.x; v[1] = (__bf16)a.y; v[2] = (__bf16)a.z; v[3] = (__bf16)a.w;
        v[4] = (__bf16)c.x; v[5] = (__bf16)c.y; v[6] = (__bf16)c.z; v[7] = (__bf16)c.w;
        Ubf[i] = v;
    }
}

// ---------------- GEMM: A(32768,512) bf16 x Bt(512,512) bf16 (N,K) ----------------
// B-RESIDENT / BARRIER-FREE structure. Seven K-loop schedules (R2-R14) all
// landed 98-105us total: the invariant cost was the per-K-step all-waves
// barrier drain. Here the 128-col B-panel (128x512x2B = 128KB) fits LDS, so:
// load it ONCE (one barrier ever), keep it resident, and read A fragments
// DIRECTLY from global (L2: each A row is read by the 4 col-panels, adjacent
// in the XCD remap). K-loop = 8 a-loads + 8 ds_reads + 32 MFMA, fully
// unrolled, ZERO barriers -> compiler pipelines freely across K-steps (m114).
// Block 256x128, 8 waves x (64x64) = R13's validated wave tile + epilogue.
// Grid 512 = 128 row-groups x 4 col-panels; 1 block/CU; 2 waves/SIMD.
// B swizzle: slot ^ (row&7) involution (rule #21, source-side on gload_lds,
// same XOR on read; 2-way bank conflict = free). A ping-pong a[2][8], static
// indices after unroll (rule #20).
// FUSE=false: out bf16 (Bu). FUSE=true: out f32 = acc + D[col]*Ubf[o].
template<bool FUSE>
__global__ __launch_bounds__(512, 2)
void gemm_bt_kernel(const __bf16* __restrict__ A, const __bf16* __restrict__ Bt,
                    void* __restrict__ CoutV, const float* __restrict__ Dvec,
                    const __bf16* __restrict__ Ubf) {
    const int K = NP2, N = NP2;
    __shared__ __align__(16) __bf16 Bs[128 * 512];      // 128 KB resident panel
    const int t = threadIdx.x;
    const int l = t & 63;
    const int w = t >> 6;           // wave 0..7
    const int wr = w >> 1;          // 0..3 (64-row band of 256)
    const int wc = w & 1;           // 0..1 (64-col half of 128)
    // XCD-aware bijective remap: 512 blocks = 8 XCDs * 64 slots; within an
    // XCD, 4 consecutive slots = same rows x 4 col-panels (A L2 reuse).
    const int b    = blockIdx.x;
    const int n_sw = (b & 7) * 64 + (b >> 3);
    const int row0 = (n_sw >> 2) * 256;
    const int col0 = (n_sw & 3) * 128;
    const int lr = l & 15;
    const int lk = (l >> 4) * 8;    // bf16 offset within a 32-col kk-half

    // ---- one-time B panel load: 8192 16B-chunks / 512 thr = 16 per thread.
    // dest wave-linear (chunk*16); source slot pre-swizzled (rule #21).
#pragma unroll
    for (int i = 0; i < 16; ++i) {
        int chunk = i * 512 + t;
        int r = chunk >> 6;             // panel row 0..127
        int s = chunk & 63;             // dest 16B slot
        gload_lds16(Bt + (size_t)(col0 + r) * K + ((s ^ (r & 7)) << 3),
                    Bs + chunk * 8);
    }
    asm volatile("s_waitcnt vmcnt(0)" ::: "memory");
    __builtin_amdgcn_s_barrier();       // the only barrier in this kernel

    f32x4 acc[4][4] = {};
    bf16x8 a[2][8];
    auto LOADA = [&](int buf, int tt) {
#pragma unroll
        for (int kk2 = 0; kk2 < 2; ++kk2)
#pragma unroll
            for (int m = 0; m < 4; ++m)
                a[buf][kk2 * 4 + m] = *reinterpret_cast<const bf16x8*>(
                    A + (size_t)(row0 + wr * 64 + m * 16 + lr) * K
                      + tt * 64 + kk2 * 32 + lk);
    };

    LOADA(0, 0);
#pragma unroll
    for (int tt = 0; tt < 8; ++tt) {
        const int cur = tt & 1;
        if (tt < 7) LOADA(cur ^ 1, tt + 1);     // next tile's A in flight
#pragma unroll
        for (int kk2 = 0; kk2 < 2; ++kk2) {
            bf16x8 b2[4];
#pragma unroll
            for (int n = 0; n < 4; ++n) {
                int row = wc * 64 + n * 16 + lr;
                int sl  = tt * 8 + kk2 * 4 + (l >> 4);      // logical 16B slot
                b2[n] = *reinterpret_cast<const bf16x8*>(
                    &Bs[row * 512 + ((sl ^ (row & 7)) << 3)]);
            }
#pragma unroll
            for (int m = 0; m < 4; ++m)
#pragma unroll
                for (int n = 0; n < 4; ++n)
                    acc[m][n] = __builtin_amdgcn_mfma_f32_16x16x32_bf16(
                        a[cur][kk2 * 4 + m], b2[n], acc[m][n], 0, 0, 0);
        }
    }

    // ---- epilogue: direct stores (R13-validated pattern, 16-lane runs) ----
    const int lg = (l >> 4) * 4;
#pragma unroll
    for (int m = 0; m < 4; ++m) {
#pragma unroll
        for (int n = 0; n < 4; ++n) {
            int col = col0 + wc * 64 + n * 16 + lr;
#pragma unroll
            for (int j = 0; j < 4; ++j) {
                int row = row0 + wr * 64 + m * 16 + lg + j;
                size_t o = (size_t)row * N + col;
                if (FUSE) {
                    ((float*)CoutV)[o] = acc[m][n][j] + Dvec[col] * (float)Ubf[o];
                } else {
                    ((__bf16*)CoutV)[o] = (__bf16)acc[m][n][j];
                }
            }
        }
    }
}

// ---------------- chunked scan (Bu bf16; 128 threads, 2 channels/thread) ----------------
// Level 0: per-chunk totals. Fc[g*128+t] = (xr0, xi0, xr1, xi1) for channels 2t, 2t+1.
__global__ void scanA_kernel(const __bf16* __restrict__ Bu, const float* __restrict__ par,
                             float4* __restrict__ Fc) {
    int g = blockIdx.x;
    int t = threadIdx.x;                // 0..127
    int p0 = 2 * t;
    float ar0 = par[p0], ai0 = par[256 + p0];
    float ar1 = par[p0 + 1], ai1 = par[256 + p0 + 1];
    const __bf16* bu = Bu + (size_t)g * CHUNK * NP2;
    float xr0 = 0.f, xi0 = 0.f, xr1 = 0.f, xi1 = 0.f;
#pragma unroll 4
    for (int i = 0; i < CHUNK; ++i) {
        bf16x2 re = *reinterpret_cast<const bf16x2*>(bu + i * NP2 + p0);
        bf16x2 im = *reinterpret_cast<const bf16x2*>(bu + i * NP2 + 256 + p0);
        float nr0 = fmaf(ar0, xr0, fmaf(-ai0, xi0, (float)re[0]));
        float ni0 = fmaf(ar0, xi0, fmaf( ai0, xr0, (float)im[0]));
        float nr1 = fmaf(ar1, xr1, fmaf(-ai1, xi1, (float)re[1]));
        float ni1 = fmaf(ar1, xi1, fmaf( ai1, xr1, (float)im[1]));
        xr0 = nr0; xi0 = ni0; xr1 = nr1; xi1 = ni1;
    }
    float4 f; f.x = xr0; f.y = xi0; f.z = xr1; f.w = xi1;
    Fc[g * 128 + t] = f;
}

// Level 1: 32 blocks; block s scans its 32 chunks with Lbar^32. Writes
// within-super exclusive prefixes Lc[g] and super totals Tc[s].
__global__ void scanB1_kernel(const float4* __restrict__ Fc, const float* __restrict__ par,
                              float4* __restrict__ Lc, float4* __restrict__ Tc) {
    int s = blockIdx.x;
    int t = threadIdx.x;                // 0..127
    int p0 = 2 * t;
    float pr0 = par[1024 + p0], pi0 = par[1280 + p0];
    float pr1 = par[1024 + p0 + 1], pi1 = par[1280 + p0 + 1];
    float er0 = 0.f, ei0 = 0.f, er1 = 0.f, ei1 = 0.f;
    int base = s * 32;
#pragma unroll
    for (int j = 0; j < 32; ++j) {
        float4 e; e.x = er0; e.y = ei0; e.z = er1; e.w = ei1;
        Lc[(base + j) * 128 + t] = e;
        float4 f = Fc[(base + j) * 128 + t];
        float nr0 = fmaf(pr0, er0, fmaf(-pi0, ei0, f.x));
        float ni0 = fmaf(pr0, ei0, fmaf( pi0, er0, f.y));
        float nr1 = fmaf(pr1, er1, fmaf(-pi1, ei1, f.z));
        float ni1 = fmaf(pr1, ei1, fmaf( pi1, er1, f.w));
        er0 = nr0; ei0 = ni0; er1 = nr1; ei1 = ni1;
    }
    float4 tt; tt.x = er0; tt.y = ei0; tt.z = er1; tt.w = ei1;
    Tc[s * 128 + t] = tt;
}

// Final: E[s] = exclusive scan over super totals (<=31 iters, Lbar^1024);
// carry = Lbar^(32k) * E[s] + Lc[g]; 32-row replay writes xs (bf16).
__global__ void scanC_kernel(const __bf16* __restrict__ Bu, const float* __restrict__ par,
                             const float4* __restrict__ Lc, const float4* __restrict__ Tc,
                             __bf16* __restrict__ xs) {
    int g = blockIdx.x;
    int t = threadIdx.x;                // 0..127
    int s = g >> 5, k = g & 31;
    int p0 = 2 * t;
    float ar0 = par[p0], ai0 = par[256 + p0];
    float ar1 = par[p0 + 1], ai1 = par[256 + p0 + 1];
    float ldr0 = par[1536 + p0], ldi0 = par[1792 + p0];
    float ldr1 = par[1536 + p0 + 1], ldi1 = par[1792 + p0 + 1];
    // Lbar^1024 per channel
    float e10 = expf(1024.0f * ldr0), ph10 = 1024.0f * ldi0;
    float q1r0 = e10 * cosf(ph10), q1i0 = e10 * sinf(ph10);
    float e11 = expf(1024.0f * ldr1), ph11 = 1024.0f * ldi1;
    float q1r1 = e11 * cosf(ph11), q1i1 = e11 * sinf(ph11);
    // E[s]: exclusive scan over super totals
    float er0 = 0.f, ei0 = 0.f, er1 = 0.f, ei1 = 0.f;
    for (int s2 = 0; s2 < s; ++s2) {
        float4 f = Tc[s2 * 128 + t];
        float nr0 = fmaf(q1r0, er0, fmaf(-q1i0, ei0, f.x));
        float ni0 = fmaf(q1r0, ei0, fmaf( q1i0, er0, f.y));
        float nr1 = fmaf(q1r1, er1, fmaf(-q1i1, ei1, f.z));
        float ni1 = fmaf(q1r1, ei1, fmaf( q1i1, er1, f.w));
        er0 = nr0; ei0 = ni0; er1 = nr1; ei1 = ni1;
    }
    // Lbar^(32k) per channel
    float kk = (float)(32 * k);
    float ek0 = expf(kk * ldr0), phk0 = kk * ldi0;
    float qr0 = ek0 * cosf(phk0), qi0 = ek0 * sinf(phk0);
    float ek1 = expf(kk * ldr1), phk1 = kk * ldi1;
    float qr1 = ek1 * cosf(phk1), qi1 = ek1 * sinf(phk1);
    float4 l0 = Lc[g * 128 + t];
    float xr0 = fmaf(qr0, er0, fmaf(-qi0, ei0, l0.x));
    float xi0 = fmaf(qr0, ei0, fmaf( qi0, er0, l0.y));
    float xr1 = fmaf(qr1, er1, fmaf(-qi1, ei1, l0.z));
    float xi1 = fmaf(qr1, ei1, fmaf( qi1, er1, l0.w));
    const __bf16* bu = Bu + (size_t)g * CHUNK * NP2;
    __bf16* xo = xs + (size_t)g * CHUNK * NP2;
#pragma unroll 4
    for (int i = 0; i < CHUNK; ++i) {
        bf16x2 re = *reinterpret_cast<const bf16x2*>(bu + i * NP2 + p0);
        bf16x2 im = *reinterpret_cast<const bf16x2*>(bu + i * NP2 + 256 + p0);
        float nr0 = fmaf(ar0, xr0, fmaf(-ai0, xi0, (float)re[0]));
        float ni0 = fmaf(ar0, xi0, fmaf( ai0, xr0, (float)im[0]));
        float nr1 = fmaf(ar1, xr1, fmaf(-ai1, xi1, (float)re[1]));
        float ni1 = fmaf(ar1, xi1, fmaf( ai1, xr1, (float)im[1]));
        xr0 = nr0; xi0 = ni0; xr1 = nr1; xi1 = ni1;
        bf16x2 wre; wre[0] = (__bf16)xr0; wre[1] = (__bf16)xr1;
        bf16x2 wim; wim[0] = (__bf16)xi0; wim[1] = (__bf16)xi1;
        *reinterpret_cast<bf16x2*>(xo + i * NP2 + p0)       = wre;
        *reinterpret_cast<bf16x2*>(xo + i * NP2 + 256 + p0) = wim;
    }
}

extern "C" void kernel_launch(void* const* d_in, const int* in_sizes, int n_in,
                              void* d_out, int out_size, void* d_ws, size_t ws_size,
                              hipStream_t stream) {
    const float* u   = (const float*)d_in[0];
    const float* Lre = (const float*)d_in[1];
    const float* Lim = (const float*)d_in[2];
    const float* Bre = (const float*)d_in[3];
    const float* Bim = (const float*)d_in[4];
    const float* Cre = (const float*)d_in[5];
    const float* Cim = (const float*)d_in[6];
    const float* Dv  = (const float*)d_in[7];
    const float* lst = (const float*)d_in[8];

    char* w = (char*)d_ws;
    size_t off = 0;
    float* par = (float*)(w + off);      off += 16 * 1024;
    __bf16* Btm = (__bf16*)(w + off);    off += (size_t)NP2 * NP2 * 2;      // 512 KB
    __bf16* Ctm = (__bf16*)(w + off);    off += (size_t)NP2 * NP2 * 2;      // 512 KB
    float4* Fc = (float4*)(w + off);     off += (size_t)NCHUNK * 128 * 16;  // 2 MB
    float4* Lc = (float4*)(w + off);     off += (size_t)NCHUNK * 128 * 16;  // 2 MB
    float4* Tc = (float4*)(w + off);     off += (size_t)NSUPER * 128 * 16;  // 64 KB
    __bf16* Ubf = (__bf16*)(w + off);    off += (size_t)L_SEQ * H_DIM * 2;  // 32 MB (bf16 u)
    __bf16* Xs  = (__bf16*)(w + off);    off += (size_t)L_SEQ * NP2 * 2;    // 32 MB (xs)
    if (ws_size < off) return;  // fail loudly (output stays poisoned)

    // Bu: bf16 L x 2P (32 MB) in the lower half of d_out; GEMM2 overwrites
    // all of d_out (f32 output) afterwards.
    __bf16* Bu = (__bf16*)d_out;

    setup_kernel  <<<9217, 256, 0, stream>>>(Lre, Lim, lst, Bre, Bim, Cre, Cim,
                                             (const float4*)u, par, Btm, Ctm, (bf16x8*)Ubf);
    gemm_bt_kernel<false><<<512, 512, 0, stream>>>(Ubf, Btm, (void*)Bu, nullptr, nullptr);
    scanA_kernel  <<<NCHUNK, 128, 0, stream>>>(Bu, par, Fc);
    scanB1_kernel <<<NSUPER, 128, 0, stream>>>(Fc, par, Lc, Tc);
    scanC_kernel  <<<NCHUNK, 128, 0, stream>>>(Bu, par, Lc, Tc, Xs);
    gemm_bt_kernel<true><<<512, 512, 0, stream>>>(Xs, Ctm, d_out, Dv, Ubf);
}

// Round 16
// 98.399 us; speedup vs baseline: 1.3290x; 1.3290x over previous
//
#include <hip/hip_runtime.h>
#include <cstdint>
#include <cstddef>

typedef __bf16 bf16x8 __attribute__((ext_vector_type(8)));
typedef __bf16 bf16x2 __attribute__((ext_vector_type(2)));
typedef float f32x4 __attribute__((ext_vector_type(4)));

#define L_SEQ 32768
#define H_DIM 512
#define P_DIM 256
#define NP2   512      // 2P = K and N of both GEMMs
#define CHUNK 32
#define NCHUNK 1024    // L / CHUNK
#define NSUPER 32      // NCHUNK / 32

__device__ __forceinline__ void gload_lds16(const void* g, void* l) {
    __builtin_amdgcn_global_load_lds(
        (const __attribute__((address_space(1))) void*)g,
        (__attribute__((address_space(3))) void*)l,
        16, 0, 0);
}

// ---------------- fused setup: prep (block 0) | build B/C (blocks 1..1024) |
// cast u->bf16 (blocks 1025..9216). Builders recompute coef inline (p uniform
// per block -> scalar transcendentals, free).
// par layout (floats): [0]=Ar [256]=Ai [1024]=PowR(Lbar^32) [1280]=PowI
//                      [1536]=ldr [1792]=ldi
__global__ void setup_kernel(const float* __restrict__ Lre, const float* __restrict__ Lim,
                             const float* __restrict__ lstep,
                             const float* __restrict__ Bre, const float* __restrict__ Bim,
                             const float* __restrict__ Cre, const float* __restrict__ Cim,
                             const float4* __restrict__ uin,
                             float* __restrict__ par,
                             __bf16* __restrict__ Bt, __bf16* __restrict__ Ct,
                             bf16x8* __restrict__ Ubf) {
    int b = blockIdx.x;
    if (b == 0) {
        int p = threadIdx.x;
        float lr = fminf(Lre[p], -1e-4f);       // clip_eigs
        float li = Lim[p];
        float st = expf(lstep[p]);
        float ldr = lr * st;
        float ldi = li * st;
        float er = expf(ldr);
        par[p]        = er * cosf(ldi);         // Ar
        par[256 + p]  = er * sinf(ldi);         // Ai
        float e32  = expf((float)CHUNK * ldr);
        float ph32 = (float)CHUNK * ldi;
        par[1024 + p] = e32 * cosf(ph32);       // PowR = Re(Lbar^32)
        par[1280 + p] = e32 * sinf(ph32);       // PowI
        par[1536 + p] = ldr;
        par[1792 + p] = ldi;
    } else if (b <= 1024) {
        int bb = b - 1;
        if (bb < 512) {
            int idx = bb * 256 + threadIdx.x;   // [0, P*H)
            int p = idx >> 9;                   // uniform per block
            float lr = fminf(Lre[p], -1e-4f);
            float li = Lim[p];
            float st = expf(lstep[p]);
            float er = expf(lr * st);
            float ar = er * cosf(li * st);
            float ai = er * sinf(li * st);
            float den = lr * lr + li * li;
            float mr = ar - 1.0f, mi = ai;
            float cr = (mr * lr + mi * li) / den;   // coef = (Lbar-1)/Lambda
            float ci = (mi * lr - mr * li) / den;
            float br = Bre[idx], bi = Bim[idx];
            int h = idx & 511;
            Bt[(size_t)p * NP2 + h]         = (__bf16)(cr * br - ci * bi);
            Bt[(size_t)(256 + p) * NP2 + h] = (__bf16)(cr * bi + ci * br);
        } else {
            int idx = (bb - 512) * 256 + threadIdx.x;   // [0, H*P)
            int h = idx >> 8;
            int q = idx & 255;
            Ct[(size_t)h * NP2 + q]       = (__bf16)( 2.0f * Cre[idx]);
            Ct[(size_t)h * NP2 + 256 + q] = (__bf16)(-2.0f * Cim[idx]);
        }
    } else {
        int i = (b - 1025) * 256 + threadIdx.x;     // [0, L*H/8)
        float4 a = uin[2 * i], c = uin[2 * i + 1];
        bf16x8 v;
        v[0] = (__bf16)a.x; v[1] = (__bf16)a.y; v[2] = (__bf16)a.z; v[3] = (__bf16)a.w;
        v[4] = (__bf16)c.x; v[5] = (__bf16)c.y; v[6] = (__bf16)c.z; v[7] = (__bf16)c.w;
        Ubf[i] = v;
    }
}

// ---------------- GEMM: A(M,512) bf16 x Bt(512,512) bf16 (N,K), 128x128 tile, BK=64 ----------------
// R13 config — best measured (98.3us total). At its LDS-BW roofline for this
// fragment scheme: per CU per K-step 256KB ds_read vs ~307cy MFMA; eight
// schedule variants (R2-R15) all landed >= this. Direct-store epilogue
// (16-lane 32B runs merge; WRITE_SIZE = 32MB exact).
// A: 3 buffers (2 ahead); B: 2 buffers (1 ahead, L2-resident). LDS 80KB,
// 2 blocks/CU. vmcnt ledger (4 loads/unit; per-iter issue B(t+1), A(t+2)):
// steady queue at wait = [A(t),B(t),A(t+1),B(t+1),A(t+2)] = 20 -> vmcnt(12)
// drains A(t)+B(t); ks=6 -> vmcnt(8); ks=7 -> vmcnt(0). Overwrites fenced by
// trailing barrier. Full 8-slot XOR source-side swizzle (rule #21) +
// swizzled reads (bank conflicts = 0, verified R5-R13).
// FUSE=false: out bf16 (Bu). FUSE=true: out f32 = acc + D[col]*Ubf[o].
template<bool FUSE>
__global__ __launch_bounds__(256)
void gemm_bt_kernel(const __bf16* __restrict__ A, const __bf16* __restrict__ Bt,
                    void* __restrict__ CoutV, const float* __restrict__ Dvec,
                    const __bf16* __restrict__ Ubf) {
    const int K = NP2, N = NP2;
    __shared__ __align__(16) __bf16 As[3][128 * 64];
    __shared__ __align__(16) __bf16 Bs[2][128 * 64];
    const int t = threadIdx.x;
    const int l = t & 63;
    const int w = t >> 6;
    const int wr = w >> 1, wc = w & 1;
    // XCD-aware bijective remap: 1024 blocks = 8 XCDs * 128 slots
    const int b    = blockIdx.x;
    const int n_sw = (b & 7) * 128 + (b >> 3);
    const int row0 = (n_sw >> 2) * 128;
    const int col0 = (n_sw & 3) * 128;
    const int lr = l & 15;
    const int lk = (l >> 4) * 8;
    f32x4 acc[4][4] = {};

    auto STAGE_A = [&](int buf, int k0) {
#pragma unroll
        for (int i = 0; i < 4; ++i) {
            int off = i * 256 + t;
            int r  = off >> 3;
            int ce = ((off & 7) ^ (r & 7)) * 8;
            gload_lds16(A + (size_t)(row0 + r) * K + (k0 + ce), &As[buf][off * 8]);
        }
    };
    auto STAGE_B = [&](int buf, int k0) {
#pragma unroll
        for (int i = 0; i < 4; ++i) {
            int off = i * 256 + t;
            int r  = off >> 3;
            int ce = ((off & 7) ^ (r & 7)) * 8;
            gload_lds16(Bt + (size_t)(col0 + r) * K + (k0 + ce), &Bs[buf][off * 8]);
        }
    };

    auto COMPUTE = [&](int ba, int bb) {
#pragma unroll
        for (int kk = 0; kk < 64; kk += 32) {
            bf16x8 a[4], b2[4];
            const int ls = (kk + lk) >> 3;
#pragma unroll
            for (int m = 0; m < 4; ++m) {
                int row = wr * 64 + m * 16 + lr;
                a[m] = *reinterpret_cast<const bf16x8*>(&As[ba][row * 64 + ((ls ^ (row & 7)) << 3)]);
            }
#pragma unroll
            for (int n = 0; n < 4; ++n) {
                int row = wc * 64 + n * 16 + lr;
                b2[n] = *reinterpret_cast<const bf16x8*>(&Bs[bb][row * 64 + ((ls ^ (row & 7)) << 3)]);
            }
            __builtin_amdgcn_s_setprio(1);
#pragma unroll
            for (int m = 0; m < 4; ++m)
#pragma unroll
                for (int n = 0; n < 4; ++n)
                    acc[m][n] = __builtin_amdgcn_mfma_f32_16x16x32_bf16(a[m], b2[n], acc[m][n], 0, 0, 0);
            __builtin_amdgcn_s_setprio(0);
        }
    };

    // prologue: A0, B0, A1  (queue = 12)
    STAGE_A(0, 0);
    STAGE_B(0, 0);
    STAGE_A(1, 64);
#pragma unroll
    for (int ks = 0; ks < 8; ++ks) {
        if (ks + 1 < 8) STAGE_B((ks + 1) & 1, (ks + 1) * 64);
        if (ks + 2 < 8) STAGE_A((ks + 2) % 3, (ks + 2) * 64);
        if (ks <= 5)      { asm volatile("s_waitcnt vmcnt(12)" ::: "memory"); }
        else if (ks == 6) { asm volatile("s_waitcnt vmcnt(8)"  ::: "memory"); }
        else              { asm volatile("s_waitcnt vmcnt(0)"  ::: "memory"); }
        __builtin_amdgcn_s_barrier();           // A(ks),B(ks) staged by ALL waves
        __builtin_amdgcn_sched_barrier(0);
        COMPUTE(ks % 3, ks & 1);
        __builtin_amdgcn_sched_barrier(0);
        __builtin_amdgcn_s_barrier();           // all waves done reading bufs of tile ks
    }

    const int lg = (l >> 4) * 4;
#pragma unroll
    for (int m = 0; m < 4; ++m) {
#pragma unroll
        for (int n = 0; n < 4; ++n) {
            int col = col0 + wc * 64 + n * 16 + lr;
#pragma unroll
            for (int j = 0; j < 4; ++j) {
                int row = row0 + wr * 64 + m * 16 + lg + j;
                size_t o = (size_t)row * N + col;
                if (FUSE) {
                    ((float*)CoutV)[o] = acc[m][n][j] + Dvec[col] * (float)Ubf[o];
                } else {
                    ((__bf16*)CoutV)[o] = (__bf16)acc[m][n][j];
                }
            }
        }
    }
}

// ---------------- chunked scan (Bu bf16; 128 threads, 2 channels/thread) ----------------
// Level 0: per-chunk totals. Fc[g*128+t] = (xr0, xi0, xr1, xi1) for channels 2t, 2t+1.
__global__ void scanA_kernel(const __bf16* __restrict__ Bu, const float* __restrict__ par,
                             float4* __restrict__ Fc) {
    int g = blockIdx.x;
    int t = threadIdx.x;                // 0..127
    int p0 = 2 * t;
    float ar0 = par[p0], ai0 = par[256 + p0];
    float ar1 = par[p0 + 1], ai1 = par[256 + p0 + 1];
    const __bf16* bu = Bu + (size_t)g * CHUNK * NP2;
    float xr0 = 0.f, xi0 = 0.f, xr1 = 0.f, xi1 = 0.f;
#pragma unroll 4
    for (int i = 0; i < CHUNK; ++i) {
        bf16x2 re = *reinterpret_cast<const bf16x2*>(bu + i * NP2 + p0);
        bf16x2 im = *reinterpret_cast<const bf16x2*>(bu + i * NP2 + 256 + p0);
        float nr0 = fmaf(ar0, xr0, fmaf(-ai0, xi0, (float)re[0]));
        float ni0 = fmaf(ar0, xi0, fmaf( ai0, xr0, (float)im[0]));
        float nr1 = fmaf(ar1, xr1, fmaf(-ai1, xi1, (float)re[1]));
        float ni1 = fmaf(ar1, xi1, fmaf( ai1, xr1, (float)im[1]));
        xr0 = nr0; xi0 = ni0; xr1 = nr1; xi1 = ni1;
    }
    float4 f; f.x = xr0; f.y = xi0; f.z = xr1; f.w = xi1;
    Fc[g * 128 + t] = f;
}

// Level 1: 32 blocks; block s scans its 32 chunks with Lbar^32. Writes
// within-super exclusive prefixes Lc[g] and super totals Tc[s].
__global__ void scanB1_kernel(const float4* __restrict__ Fc, const float* __restrict__ par,
                              float4* __restrict__ Lc, float4* __restrict__ Tc) {
    int s = blockIdx.x;
    int t = threadIdx.x;                // 0..127
    int p0 = 2 * t;
    float pr0 = par[1024 + p0], pi0 = par[1280 + p0];
    float pr1 = par[1024 + p0 + 1], pi1 = par[1280 + p0 + 1];
    float er0 = 0.f, ei0 = 0.f, er1 = 0.f, ei1 = 0.f;
    int base = s * 32;
#pragma unroll
    for (int j = 0; j < 32; ++j) {
        float4 e; e.x = er0; e.y = ei0; e.z = er1; e.w = ei1;
        Lc[(base + j) * 128 + t] = e;
        float4 f = Fc[(base + j) * 128 + t];
        float nr0 = fmaf(pr0, er0, fmaf(-pi0, ei0, f.x));
        float ni0 = fmaf(pr0, ei0, fmaf( pi0, er0, f.y));
        float nr1 = fmaf(pr1, er1, fmaf(-pi1, ei1, f.z));
        float ni1 = fmaf(pr1, ei1, fmaf( pi1, er1, f.w));
        er0 = nr0; ei0 = ni0; er1 = nr1; ei1 = ni1;
    }
    float4 tt; tt.x = er0; tt.y = ei0; tt.z = er1; tt.w = ei1;
    Tc[s * 128 + t] = tt;
}

// Final: E[s] = exclusive scan over super totals (<=31 iters, Lbar^1024);
// carry = Lbar^(32k) * E[s] + Lc[g]; 32-row replay writes xs (bf16).
__global__ void scanC_kernel(const __bf16* __restrict__ Bu, const float* __restrict__ par,
                             const float4* __restrict__ Lc, const float4* __restrict__ Tc,
                             __bf16* __restrict__ xs) {
    int g = blockIdx.x;
    int t = threadIdx.x;                // 0..127
    int s = g >> 5, k = g & 31;
    int p0 = 2 * t;
    float ar0 = par[p0], ai0 = par[256 + p0];
    float ar1 = par[p0 + 1], ai1 = par[256 + p0 + 1];
    float ldr0 = par[1536 + p0], ldi0 = par[1792 + p0];
    float ldr1 = par[1536 + p0 + 1], ldi1 = par[1792 + p0 + 1];
    // Lbar^1024 per channel
    float e10 = expf(1024.0f * ldr0), ph10 = 1024.0f * ldi0;
    float q1r0 = e10 * cosf(ph10), q1i0 = e10 * sinf(ph10);
    float e11 = expf(1024.0f * ldr1), ph11 = 1024.0f * ldi1;
    float q1r1 = e11 * cosf(ph11), q1i1 = e11 * sinf(ph11);
    // E[s]: exclusive scan over super totals
    float er0 = 0.f, ei0 = 0.f, er1 = 0.f, ei1 = 0.f;
    for (int s2 = 0; s2 < s; ++s2) {
        float4 f = Tc[s2 * 128 + t];
        float nr0 = fmaf(q1r0, er0, fmaf(-q1i0, ei0, f.x));
        float ni0 = fmaf(q1r0, ei0, fmaf( q1i0, er0, f.y));
        float nr1 = fmaf(q1r1, er1, fmaf(-q1i1, ei1, f.z));
        float ni1 = fmaf(q1r1, ei1, fmaf( q1i1, er1, f.w));
        er0 = nr0; ei0 = ni0; er1 = nr1; ei1 = ni1;
    }
    // Lbar^(32k) per channel
    float kk = (float)(32 * k);
    float ek0 = expf(kk * ldr0), phk0 = kk * ldi0;
    float qr0 = ek0 * cosf(phk0), qi0 = ek0 * sinf(phk0);
    float ek1 = expf(kk * ldr1), phk1 = kk * ldi1;
    float qr1 = ek1 * cosf(phk1), qi1 = ek1 * sinf(phk1);
    float4 l0 = Lc[g * 128 + t];
    float xr0 = fmaf(qr0, er0, fmaf(-qi0, ei0, l0.x));
    float xi0 = fmaf(qr0, ei0, fmaf( qi0, er0, l0.y));
    float xr1 = fmaf(qr1, er1, fmaf(-qi1, ei1, l0.z));
    float xi1 = fmaf(qr1, ei1, fmaf( qi1, er1, l0.w));
    const __bf16* bu = Bu + (size_t)g * CHUNK * NP2;
    __bf16* xo = xs + (size_t)g * CHUNK * NP2;
#pragma unroll 4
    for (int i = 0; i < CHUNK; ++i) {
        bf16x2 re = *reinterpret_cast<const bf16x2*>(bu + i * NP2 + p0);
        bf16x2 im = *reinterpret_cast<const bf16x2*>(bu + i * NP2 + 256 + p0);
        float nr0 = fmaf(ar0, xr0, fmaf(-ai0, xi0, (float)re[0]));
        float ni0 = fmaf(ar0, xi0, fmaf( ai0, xr0, (float)im[0]));
        float nr1 = fmaf(ar1, xr1, fmaf(-ai1, xi1, (float)re[1]));
        float ni1 = fmaf(ar1, xi1, fmaf( ai1, xr1, (float)im[1]));
        xr0 = nr0; xi0 = ni0; xr1 = nr1; xi1 = ni1;
        bf16x2 wre; wre[0] = (__bf16)xr0; wre[1] = (__bf16)xr1;
        bf16x2 wim; wim[0] = (__bf16)xi0; wim[1] = (__bf16)xi1;
        *reinterpret_cast<bf16x2*>(xo + i * NP2 + p0)       = wre;
        *reinterpret_cast<bf16x2*>(xo + i * NP2 + 256 + p0) = wim;
    }
}

extern "C" void kernel_launch(void* const* d_in, const int* in_sizes, int n_in,
                              void* d_out, int out_size, void* d_ws, size_t ws_size,
                              hipStream_t stream) {
    const float* u   = (const float*)d_in[0];
    const float* Lre = (const float*)d_in[1];
    const float* Lim = (const float*)d_in[2];
    const float* Bre = (const float*)d_in[3];
    const float* Bim = (const float*)d_in[4];
    const float* Cre = (const float*)d_in[5];
    const float* Cim = (const float*)d_in[6];
    const float* Dv  = (const float*)d_in[7];
    const float* lst = (const float*)d_in[8];

    char* w = (char*)d_ws;
    size_t off = 0;
    float* par = (float*)(w + off);      off += 16 * 1024;
    __bf16* Btm = (__bf16*)(w + off);    off += (size_t)NP2 * NP2 * 2;      // 512 KB
    __bf16* Ctm = (__bf16*)(w + off);    off += (size_t)NP2 * NP2 * 2;      // 512 KB
    float4* Fc = (float4*)(w + off);     off += (size_t)NCHUNK * 128 * 16;  // 2 MB
    float4* Lc = (float4*)(w + off);     off += (size_t)NCHUNK * 128 * 16;  // 2 MB
    float4* Tc = (float4*)(w + off);     off += (size_t)NSUPER * 128 * 16;  // 64 KB
    __bf16* Ubf = (__bf16*)(w + off);    off += (size_t)L_SEQ * H_DIM * 2;  // 32 MB (bf16 u)
    __bf16* Xs  = (__bf16*)(w + off);    off += (size_t)L_SEQ * NP2 * 2;    // 32 MB (xs)
    if (ws_size < off) return;  // fail loudly (output stays poisoned)

    // Bu: bf16 L x 2P (32 MB) in the lower half of d_out; GEMM2 overwrites
    // all of d_out (f32 output) afterwards.
    __bf16* Bu = (__bf16*)d_out;

    setup_kernel  <<<9217, 256, 0, stream>>>(Lre, Lim, lst, Bre, Bim, Cre, Cim,
                                             (const float4*)u, par, Btm, Ctm, (bf16x8*)Ubf);
    gemm_bt_kernel<false><<<1024, 256, 0, stream>>>(Ubf, Btm, (void*)Bu, nullptr, nullptr);
    scanA_kernel  <<<NCHUNK, 128, 0, stream>>>(Bu, par, Fc);
    scanB1_kernel <<<NSUPER, 128, 0, stream>>>(Fc, par, Lc, Tc);
    scanC_kernel  <<<NCHUNK, 128, 0, stream>>>(Bu, par, Lc, Tc, Xs);
    gemm_bt_kernel<true><<<1024, 256, 0, stream>>>(Xs, Ctm, d_out, Dv, Ubf);
}